// Round 4
// baseline (253.103 us; speedup 1.0000x reference)
//
#include <hip/hip_runtime.h>
#include <hip/hip_bf16.h>

// TripletLoss, N=8192, D=256 fp32, targets in [0,128).
// out[0] = mean(relu(dist_ap - dist_an + 0.3)), out[1] = mean(dist_an > dist_ap)
// dist = sqrt(clip(sq_i + sq_j - 2 dot, 1e-12)); sqrt deferred (monotone);
// d2 > 0 so uint-bit order == float order -> atomicMax/Min on unsigned.
//
// R3: A-fragments in registers (no A staging in k-loop), B through LDS with
// single-barrier double-buffer (issue next tile's lds-DMA right after the
// barrier -> drain overlaps compute). Symmetric 2-sided epilogue kept.
// Finish fused into tile_kernel via device-scope arrival counter (last block
// re-reads row results with no-op atomics -> XCD-coherence safe).

#define N 8192
#define D 256
#define MARGIN 0.3f
#define NBLK 2080  // 64*65/2 lower-triangle 128x128 tiles

typedef __bf16  bf16x8  __attribute__((ext_vector_type(8)));
typedef float   floatx4 __attribute__((ext_vector_type(4)));

__device__ __forceinline__ void load_lds16(const void* g, void* s) {
  __builtin_amdgcn_global_load_lds(
      (const __attribute__((address_space(1))) void*)g,
      (__attribute__((address_space(3))) void*)s, 16, 0, 0);
}

// ---------------- Kernel A: bf16 cast + row sq-norms + init ------------------
__global__ __launch_bounds__(256) void prep_kernel(
    const float* __restrict__ X, unsigned short* __restrict__ Xb,
    float* __restrict__ sq, unsigned* __restrict__ pmax, unsigned* __restrict__ nmin,
    unsigned* __restrict__ counter) {
  const int t = threadIdx.x;
  const int lane = t & 63, wave = t >> 6;
  const int row0 = blockIdx.x * 8 + wave * 2;
  if (blockIdx.x == 0 && t == 0) *counter = 0u;
#pragma unroll
  for (int r = 0; r < 2; ++r) {
    const int row = row0 + r;
    float4 v = *reinterpret_cast<const float4*>(X + (size_t)row * D + lane * 4);
    ushort4 h;
    {
      __hip_bfloat16 b0 = __float2bfloat16(v.x), b1 = __float2bfloat16(v.y);
      __hip_bfloat16 b2 = __float2bfloat16(v.z), b3 = __float2bfloat16(v.w);
      h.x = *reinterpret_cast<unsigned short*>(&b0);
      h.y = *reinterpret_cast<unsigned short*>(&b1);
      h.z = *reinterpret_cast<unsigned short*>(&b2);
      h.w = *reinterpret_cast<unsigned short*>(&b3);
    }
    *reinterpret_cast<ushort4*>(Xb + (size_t)row * D + lane * 4) = h;
    float s = v.x * v.x + v.y * v.y + v.z * v.z + v.w * v.w;
#pragma unroll
    for (int o = 32; o > 0; o >>= 1) s += __shfl_down(s, o);
    if (lane == 0) {
      sq[row] = s;
      pmax[row] = 0u;
      nmin[row] = 0x7F800000u;  // +inf
    }
  }
}

// ---------------- Kernel B: triangular tiles, A-in-regs, B dbuf --------------
__global__ __launch_bounds__(256, 2) void tile_kernel(
    const unsigned short* __restrict__ Xb, const float* __restrict__ sq,
    const int* __restrict__ tgt, unsigned* __restrict__ pmax, unsigned* __restrict__ nmin,
    unsigned* __restrict__ counter, float* __restrict__ out) {
  // lower-triangle decode: bi -> (by >= bx)
  const int bi = blockIdx.x;
  int by = (int)((sqrtf(8.0f * (float)bi + 1.0f) - 1.0f) * 0.5f);
  while ((by + 1) * (by + 2) / 2 <= bi) ++by;
  while (by * (by + 1) / 2 > bi) --by;
  const int bx = bi - by * (by + 1) / 2;
  const int rowBase = by * 128, colBase = bx * 128;

  const int t = threadIdx.x;
  const int lane = t & 63, wave = t >> 6;
  const int wy = wave >> 1, wx = wave & 1;
  const int quad = lane >> 4, l15 = lane & 15;

  __shared__ __align__(16) unsigned short Bs[2][128 * 32];  // 8 KB x2, XOR-swizzled
  __shared__ float sqr[128], sqc[128];
  __shared__ int   tr[128], tc[128];
  __shared__ unsigned pmL[128], nmL[128], pmLc[128], nmLc[128];
  __shared__ float ls[4], ps[4];
  __shared__ unsigned ticket;

  if (t < 128) {
    sqr[t] = sq[rowBase + t]; tr[t] = tgt[rowBase + t];
    pmL[t] = 0u; nmL[t] = 0x7F800000u;
  } else {
    int u = t - 128;
    sqc[u] = sq[colBase + u]; tc[u] = tgt[colBase + u];
    pmLc[u] = 0u; nmLc[u] = 0x7F800000u;
  }

  // ---- B staging setup (same XOR swizzle as R2; chunk p holds global chunk
  // (col=p>>2, c=(p&3)^(col&3)) so ds_read_b128 is conflict-minimal) ----
  const unsigned short* Bg = Xb + (size_t)colBase * D;
  int goffB[2], lbase[2];
#pragma unroll
  for (int it = 0; it < 2; ++it) {
    int p = t + it * 256;
    int col = p >> 2;
    int c = (p & 3) ^ (col & 3);
    goffB[it] = col * D + c * 8;
    lbase[it] = (it * 256 + wave * 64) * 16;
  }
  int bAddr[4];
#pragma unroll
  for (int nj = 0; nj < 4; ++nj) {
    int col = wx * 64 + nj * 16 + l15;
    bAddr[nj] = (col * 4 + (quad ^ (col & 3))) * 16;
  }

  // ---- A fragments in registers: a[mi][kk] covers rows wy*64+mi*16+l15,
  // k = kk*32 + quad*8 + j  (exact 16x16x32 A-operand layout) ----
  bf16x8 a[4][8];
  {
    const unsigned short* Arow = Xb + (size_t)(rowBase + wy * 64) * D;
#pragma unroll
    for (int mi = 0; mi < 4; ++mi) {
      const unsigned short* p = Arow + (mi * 16 + l15) * D + quad * 8;
#pragma unroll
      for (int kk = 0; kk < 8; ++kk)
        a[mi][kk] = *reinterpret_cast<const bf16x8*>(p + kk * 32);
    }
  }

  // prologue: issue buffer-0 loads
#pragma unroll
  for (int it = 0; it < 2; ++it)
    load_lds16(Bg + goffB[it], (char*)Bs[0] + lbase[it]);

  floatx4 acc[4][4];
#pragma unroll
  for (int mi = 0; mi < 4; ++mi)
#pragma unroll
    for (int nj = 0; nj < 4; ++nj)
      acc[mi][nj] = (floatx4){0.f, 0.f, 0.f, 0.f};

  for (int kk = 0; kk < 8; ++kk) {
    __syncthreads();  // drains loads issued one full compute-phase ago
    if (kk < 7) {
      int k0n = (kk + 1) * 32;
#pragma unroll
      for (int it = 0; it < 2; ++it)
        load_lds16(Bg + goffB[it] + k0n, (char*)Bs[(kk + 1) & 1] + lbase[it]);
    }
    const char* bbuf = (const char*)Bs[kk & 1];
    bf16x8 b[4];
#pragma unroll
    for (int nj = 0; nj < 4; ++nj)
      b[nj] = *reinterpret_cast<const bf16x8*>(bbuf + bAddr[nj]);
#pragma unroll
    for (int mi = 0; mi < 4; ++mi)
#pragma unroll
      for (int nj = 0; nj < 4; ++nj)
        acc[mi][nj] = __builtin_amdgcn_mfma_f32_16x16x32_bf16(a[mi][kk], b[nj], acc[mi][nj], 0, 0, 0);
  }

  // ---- two-sided epilogue on clipped d2 ----
  float sqc_l[4]; int tc_l[4];
#pragma unroll
  for (int nj = 0; nj < 4; ++nj) {
    int jl = wx * 64 + nj * 16 + l15;
    sqc_l[nj] = sqc[jl];
    tc_l[nj]  = tc[jl];
  }

  float pm[16], nm[16], cmP[4], cmN[4];
#pragma unroll
  for (int s = 0; s < 16; ++s) { pm[s] = 0.f; nm[s] = __builtin_huge_valf(); }
#pragma unroll
  for (int nj = 0; nj < 4; ++nj) { cmP[nj] = 0.f; cmN[nj] = __builtin_huge_valf(); }

#pragma unroll
  for (int mi = 0; mi < 4; ++mi) {
#pragma unroll
    for (int r = 0; r < 4; ++r) {
      int il = wy * 64 + mi * 16 + quad * 4 + r;
      float si = sqr[il];
      int   ti = tr[il];
      int   s  = mi * 4 + r;
#pragma unroll
      for (int nj = 0; nj < 4; ++nj) {
        float d2 = fmaxf(fmaf(-2.f, acc[mi][nj][r], si + sqc_l[nj]), 1e-12f);
        bool same = (ti == tc_l[nj]);
        float selP = same ? d2 : 0.f;                      // no-op for max
        float selN = same ? __builtin_huge_valf() : d2;    // no-op for min
        pm[s]   = fmaxf(pm[s], selP);
        nm[s]   = fminf(nm[s], selN);
        cmP[nj] = fmaxf(cmP[nj], selP);
        cmN[nj] = fminf(cmN[nj], selN);
      }
    }
  }

  // row-side halving butterfly across 16 lanes of each quad group
#pragma unroll
  for (int m = 8; m >= 1; m >>= 1) {
#pragma unroll
    for (int j = 0; j < m; ++j) {
      bool up = (l15 & m) != 0;
      float sp = up ? pm[j] : pm[j + m];
      float sn = up ? nm[j] : nm[j + m];
      float rp = __shfl_xor(sp, m);
      float rn = __shfl_xor(sn, m);
      float kp = up ? pm[j + m] : pm[j];
      float kn = up ? nm[j + m] : nm[j];
      pm[j] = fmaxf(kp, rp);
      nm[j] = fminf(kn, rn);
    }
  }
  {
    int rowIdx = wy * 64 + ((l15 >> 2) << 4) + (quad << 2) + (l15 & 3);
    atomicMax(&pmL[rowIdx], __float_as_uint(pm[0]));
    atomicMin(&nmL[rowIdx], __float_as_uint(nm[0]));
  }

  // col-side: reduce across quads
#pragma unroll
  for (int nj = 0; nj < 4; ++nj) {
    cmP[nj] = fmaxf(cmP[nj], __shfl_xor(cmP[nj], 16));
    cmP[nj] = fmaxf(cmP[nj], __shfl_xor(cmP[nj], 32));
    cmN[nj] = fminf(cmN[nj], __shfl_xor(cmN[nj], 16));
    cmN[nj] = fminf(cmN[nj], __shfl_xor(cmN[nj], 32));
  }
  {
    float vP = (quad == 0) ? cmP[0] : (quad == 1) ? cmP[1] : (quad == 2) ? cmP[2] : cmP[3];
    float vN = (quad == 0) ? cmN[0] : (quad == 1) ? cmN[1] : (quad == 2) ? cmN[2] : cmN[3];
    int colIdx = wx * 64 + quad * 16 + l15;
    atomicMax(&pmLc[colIdx], __float_as_uint(vP));
    atomicMin(&nmLc[colIdx], __float_as_uint(vN));
  }
  __syncthreads();

  if (t < 128) {
    atomicMax(&pmax[rowBase + t], pmL[t]);
    atomicMin(&nmin[rowBase + t], nmL[t]);
  } else {
    int u = t - 128;
    atomicMax(&pmax[colBase + u], pmLc[u]);
    atomicMin(&nmin[colBase + u], nmLc[u]);
  }

  // ---- fused finish: last-arriving block computes loss/prec ----
  __threadfence();
  if (t == 0) ticket = atomicAdd(counter, 1u);
  __syncthreads();
  if (ticket == NBLK - 1) {
    __threadfence();
    float lsum = 0.f, psum = 0.f;
    for (int i = t; i < N; i += 256) {
      // device-scope no-op atomics as coherent reads (XCD-safe)
      float ap = sqrtf(__uint_as_float(atomicMax(&pmax[i], 0u)));
      float an = sqrtf(__uint_as_float(atomicMin(&nmin[i], 0xFFFFFFFFu)));
      lsum += fmaxf(ap - an + MARGIN, 0.f);
      psum += (an > ap) ? 1.f : 0.f;
    }
#pragma unroll
    for (int o = 32; o > 0; o >>= 1) {
      lsum += __shfl_down(lsum, o);
      psum += __shfl_down(psum, o);
    }
    if (lane == 0) { ls[wave] = lsum; ps[wave] = psum; }
    __syncthreads();
    if (t == 0) {
      out[0] = (ls[0] + ls[1] + ls[2] + ls[3]) * (1.0f / (float)N);
      out[1] = (ps[0] + ps[1] + ps[2] + ps[3]) * (1.0f / (float)N);
    }
  }
}

extern "C" void kernel_launch(void* const* d_in, const int* in_sizes, int n_in,
                              void* d_out, int out_size, void* d_ws, size_t ws_size,
                              hipStream_t stream) {
  const float* X  = (const float*)d_in[0];
  const int* tgt  = (const int*)d_in[1];
  float* out      = (float*)d_out;

  char* ws = (char*)d_ws;
  unsigned short* Xb = (unsigned short*)ws;                    // 4 MiB
  float*    sq    = (float*)(ws + 4194304);                    // 32 KiB
  unsigned* pmax  = (unsigned*)(ws + 4194304 + 32768);         // 32 KiB
  unsigned* nmin  = (unsigned*)(ws + 4194304 + 65536);         // 32 KiB
  unsigned* cnt   = (unsigned*)(ws + 4194304 + 98304);         // 4 B

  prep_kernel<<<1024, 256, 0, stream>>>(X, Xb, sq, pmax, nmin, cnt);
  tile_kernel<<<NBLK, 256, 0, stream>>>(Xb, sq, tgt, pmax, nmin, cnt, out);
}

// Round 5
// 221.686 us; speedup vs baseline: 1.1417x; 1.1417x over previous
//
#include <hip/hip_runtime.h>
#include <hip/hip_bf16.h>

// TripletLoss, N=8192, D=256 fp32, targets in [0,128).
// out[0] = mean(relu(dist_ap - dist_an + 0.3)), out[1] = mean(dist_an > dist_ap)
// dist = sqrt(clip(sq_i + sq_j - 2 dot, 1e-12)); sqrt deferred (monotone);
// d2 > 0 so uint-bit order == float order -> atomicMax/Min on unsigned.
//
// R4: revert R3's A-in-registers (128 persistent VGPRs -> scratch spill,
// VGPR_Count=116 < 128 needed; 3.3x regression). Back to R2's LDS-staged A+B,
// but DOUBLE-BUFFERED with ONE barrier per k-iter: the DMA drained by each
// barrier was issued a full compute phase earlier -> latency hidden.
// Keep: triangular 2-sided epilogue, fused last-block finish, fat prep.

#define N 8192
#define D 256
#define MARGIN 0.3f
#define NBLK 2080  // 64*65/2 lower-triangle 128x128 tiles

typedef __bf16  bf16x8  __attribute__((ext_vector_type(8)));
typedef float   floatx4 __attribute__((ext_vector_type(4)));

__device__ __forceinline__ void load_lds16(const void* g, void* s) {
  __builtin_amdgcn_global_load_lds(
      (const __attribute__((address_space(1))) void*)g,
      (__attribute__((address_space(3))) void*)s, 16, 0, 0);
}

// ---------------- Kernel A: bf16 cast + row sq-norms + init ------------------
__global__ __launch_bounds__(256) void prep_kernel(
    const float* __restrict__ X, unsigned short* __restrict__ Xb,
    float* __restrict__ sq, unsigned* __restrict__ pmax, unsigned* __restrict__ nmin,
    unsigned* __restrict__ counter) {
  const int t = threadIdx.x;
  const int lane = t & 63, wave = t >> 6;
  const int row0 = blockIdx.x * 8 + wave * 2;
  if (blockIdx.x == 0 && t == 0) *counter = 0u;
#pragma unroll
  for (int r = 0; r < 2; ++r) {
    const int row = row0 + r;
    float4 v = *reinterpret_cast<const float4*>(X + (size_t)row * D + lane * 4);
    ushort4 h;
    {
      __hip_bfloat16 b0 = __float2bfloat16(v.x), b1 = __float2bfloat16(v.y);
      __hip_bfloat16 b2 = __float2bfloat16(v.z), b3 = __float2bfloat16(v.w);
      h.x = *reinterpret_cast<unsigned short*>(&b0);
      h.y = *reinterpret_cast<unsigned short*>(&b1);
      h.z = *reinterpret_cast<unsigned short*>(&b2);
      h.w = *reinterpret_cast<unsigned short*>(&b3);
    }
    *reinterpret_cast<ushort4*>(Xb + (size_t)row * D + lane * 4) = h;
    float s = v.x * v.x + v.y * v.y + v.z * v.z + v.w * v.w;
#pragma unroll
    for (int o = 32; o > 0; o >>= 1) s += __shfl_down(s, o);
    if (lane == 0) {
      sq[row] = s;
      pmax[row] = 0u;
      nmin[row] = 0x7F800000u;  // +inf
    }
  }
}

// ---------------- Kernel B: triangular tiles, dbuf LDS A+B, fused finish -----
__global__ __launch_bounds__(256) void tile_kernel(
    const unsigned short* __restrict__ Xb, const float* __restrict__ sq,
    const int* __restrict__ tgt, unsigned* __restrict__ pmax, unsigned* __restrict__ nmin,
    unsigned* __restrict__ counter, float* __restrict__ out) {
  // lower-triangle decode: bi -> (by >= bx)
  const int bi = blockIdx.x;
  int by = (int)((sqrtf(8.0f * (float)bi + 1.0f) - 1.0f) * 0.5f);
  while ((by + 1) * (by + 2) / 2 <= bi) ++by;
  while (by * (by + 1) / 2 > bi) --by;
  const int bx = bi - by * (by + 1) / 2;
  const int rowBase = by * 128, colBase = bx * 128;

  const int t = threadIdx.x;
  const int lane = t & 63, wave = t >> 6;
  const int wy = wave >> 1, wx = wave & 1;
  const int quad = lane >> 4, l15 = lane & 15;

  // XOR-swizzled tiles (chunk p holds global chunk (row=p>>2, c=(p&3)^(row&3)))
  __shared__ __align__(16) unsigned short As[2][128 * 32];  // 8 KB x2
  __shared__ __align__(16) unsigned short Bs[2][128 * 32];  // 8 KB x2
  __shared__ float sqr[128], sqc[128];
  __shared__ int   tr[128], tc[128];
  __shared__ unsigned pmL[128], nmL[128], pmLc[128], nmLc[128];
  __shared__ float ls[4], ps[4];
  __shared__ unsigned ticket;

  if (t < 128) {
    sqr[t] = sq[rowBase + t]; tr[t] = tgt[rowBase + t];
    pmL[t] = 0u; nmL[t] = 0x7F800000u;
  } else {
    int u = t - 128;
    sqc[u] = sq[colBase + u]; tc[u] = tgt[colBase + u];
    pmLc[u] = 0u; nmLc[u] = 0x7F800000u;
  }

  const unsigned short* Ag = Xb + (size_t)rowBase * D;
  const unsigned short* Bg = Xb + (size_t)colBase * D;

  int goff[2], lbase[2];
#pragma unroll
  for (int it = 0; it < 2; ++it) {
    int p = t + it * 256;
    int row = p >> 2;
    int c = (p & 3) ^ (row & 3);
    goff[it] = row * D + c * 8;
    lbase[it] = (it * 256 + wave * 64) * 16;
  }
  int aAddr[4], bAddr[4];
#pragma unroll
  for (int mi = 0; mi < 4; ++mi) {
    int row = wy * 64 + mi * 16 + l15;
    aAddr[mi] = (row * 4 + (quad ^ (row & 3))) * 16;
  }
#pragma unroll
  for (int nj = 0; nj < 4; ++nj) {
    int col = wx * 64 + nj * 16 + l15;
    bAddr[nj] = (col * 4 + (quad ^ (col & 3))) * 16;
  }

  // prologue: issue buffer-0 DMA
#pragma unroll
  for (int it = 0; it < 2; ++it) {
    load_lds16(Ag + goff[it], (char*)As[0] + lbase[it]);
    load_lds16(Bg + goff[it], (char*)Bs[0] + lbase[it]);
  }

  floatx4 acc[4][4];
#pragma unroll
  for (int mi = 0; mi < 4; ++mi)
#pragma unroll
    for (int nj = 0; nj < 4; ++nj)
      acc[mi][nj] = (floatx4){0.f, 0.f, 0.f, 0.f};

  for (int kk = 0; kk < 8; ++kk) {
    __syncthreads();  // drains buf[kk]'s DMA (issued one compute phase ago)
    if (kk < 7) {
      int k0n = (kk + 1) * 32;
      char* an = (char*)As[(kk + 1) & 1];
      char* bn = (char*)Bs[(kk + 1) & 1];
#pragma unroll
      for (int it = 0; it < 2; ++it) {
        load_lds16(Ag + goff[it] + k0n, an + lbase[it]);
        load_lds16(Bg + goff[it] + k0n, bn + lbase[it]);
      }
    }
    const char* abuf = (const char*)As[kk & 1];
    const char* bbuf = (const char*)Bs[kk & 1];
    bf16x8 a[4], b[4];
#pragma unroll
    for (int mi = 0; mi < 4; ++mi)
      a[mi] = *reinterpret_cast<const bf16x8*>(abuf + aAddr[mi]);
#pragma unroll
    for (int nj = 0; nj < 4; ++nj)
      b[nj] = *reinterpret_cast<const bf16x8*>(bbuf + bAddr[nj]);
#pragma unroll
    for (int mi = 0; mi < 4; ++mi)
#pragma unroll
      for (int nj = 0; nj < 4; ++nj)
        acc[mi][nj] = __builtin_amdgcn_mfma_f32_16x16x32_bf16(a[mi], b[nj], acc[mi][nj], 0, 0, 0);
  }

  // ---- two-sided epilogue on clipped d2 ----
  float sqc_l[4]; int tc_l[4];
#pragma unroll
  for (int nj = 0; nj < 4; ++nj) {
    int jl = wx * 64 + nj * 16 + l15;
    sqc_l[nj] = sqc[jl];
    tc_l[nj]  = tc[jl];
  }

  float pm[16], nm[16], cmP[4], cmN[4];
#pragma unroll
  for (int s = 0; s < 16; ++s) { pm[s] = 0.f; nm[s] = __builtin_huge_valf(); }
#pragma unroll
  for (int nj = 0; nj < 4; ++nj) { cmP[nj] = 0.f; cmN[nj] = __builtin_huge_valf(); }

#pragma unroll
  for (int mi = 0; mi < 4; ++mi) {
#pragma unroll
    for (int r = 0; r < 4; ++r) {
      int il = wy * 64 + mi * 16 + quad * 4 + r;
      float si = sqr[il];
      int   ti = tr[il];
      int   s  = mi * 4 + r;
#pragma unroll
      for (int nj = 0; nj < 4; ++nj) {
        float d2 = fmaxf(fmaf(-2.f, acc[mi][nj][r], si + sqc_l[nj]), 1e-12f);
        bool same = (ti == tc_l[nj]);
        float selP = same ? d2 : 0.f;                      // no-op for max
        float selN = same ? __builtin_huge_valf() : d2;    // no-op for min
        pm[s]   = fmaxf(pm[s], selP);
        nm[s]   = fminf(nm[s], selN);
        cmP[nj] = fmaxf(cmP[nj], selP);
        cmN[nj] = fminf(cmN[nj], selN);
      }
    }
  }

  // row-side halving butterfly across 16 lanes of each quad group
#pragma unroll
  for (int m = 8; m >= 1; m >>= 1) {
#pragma unroll
    for (int j = 0; j < m; ++j) {
      bool up = (l15 & m) != 0;
      float sp = up ? pm[j] : pm[j + m];
      float sn = up ? nm[j] : nm[j + m];
      float rp = __shfl_xor(sp, m);
      float rn = __shfl_xor(sn, m);
      float kp = up ? pm[j + m] : pm[j];
      float kn = up ? nm[j + m] : nm[j];
      pm[j] = fmaxf(kp, rp);
      nm[j] = fminf(kn, rn);
    }
  }
  {
    int rowIdx = wy * 64 + ((l15 >> 2) << 4) + (quad << 2) + (l15 & 3);
    atomicMax(&pmL[rowIdx], __float_as_uint(pm[0]));
    atomicMin(&nmL[rowIdx], __float_as_uint(nm[0]));
  }

  // col-side: reduce across quads
#pragma unroll
  for (int nj = 0; nj < 4; ++nj) {
    cmP[nj] = fmaxf(cmP[nj], __shfl_xor(cmP[nj], 16));
    cmP[nj] = fmaxf(cmP[nj], __shfl_xor(cmP[nj], 32));
    cmN[nj] = fminf(cmN[nj], __shfl_xor(cmN[nj], 16));
    cmN[nj] = fminf(cmN[nj], __shfl_xor(cmN[nj], 32));
  }
  {
    float vP = (quad == 0) ? cmP[0] : (quad == 1) ? cmP[1] : (quad == 2) ? cmP[2] : cmP[3];
    float vN = (quad == 0) ? cmN[0] : (quad == 1) ? cmN[1] : (quad == 2) ? cmN[2] : cmN[3];
    int colIdx = wx * 64 + quad * 16 + l15;
    atomicMax(&pmLc[colIdx], __float_as_uint(vP));
    atomicMin(&nmLc[colIdx], __float_as_uint(vN));
  }
  __syncthreads();

  if (t < 128) {
    atomicMax(&pmax[rowBase + t], pmL[t]);
    atomicMin(&nmin[rowBase + t], nmL[t]);
  } else {
    int u = t - 128;
    atomicMax(&pmax[colBase + u], pmLc[u]);
    atomicMin(&nmin[colBase + u], nmLc[u]);
  }

  // ---- fused finish: last-arriving block computes loss/prec ----
  __threadfence();
  if (t == 0) ticket = atomicAdd(counter, 1u);
  __syncthreads();
  if (ticket == NBLK - 1) {
    __threadfence();
    float lsum = 0.f, psum = 0.f;
    for (int i = t; i < N; i += 256) {
      // device-scope no-op atomics as coherent reads (XCD-safe)
      float ap = sqrtf(__uint_as_float(atomicMax(&pmax[i], 0u)));
      float an = sqrtf(__uint_as_float(atomicMin(&nmin[i], 0xFFFFFFFFu)));
      lsum += fmaxf(ap - an + MARGIN, 0.f);
      psum += (an > ap) ? 1.f : 0.f;
    }
#pragma unroll
    for (int o = 32; o > 0; o >>= 1) {
      lsum += __shfl_down(lsum, o);
      psum += __shfl_down(psum, o);
    }
    if (lane == 0) { ls[wave] = lsum; ps[wave] = psum; }
    __syncthreads();
    if (t == 0) {
      out[0] = (ls[0] + ls[1] + ls[2] + ls[3]) * (1.0f / (float)N);
      out[1] = (ps[0] + ps[1] + ps[2] + ps[3]) * (1.0f / (float)N);
    }
  }
}

extern "C" void kernel_launch(void* const* d_in, const int* in_sizes, int n_in,
                              void* d_out, int out_size, void* d_ws, size_t ws_size,
                              hipStream_t stream) {
  const float* X  = (const float*)d_in[0];
  const int* tgt  = (const int*)d_in[1];
  float* out      = (float*)d_out;

  char* ws = (char*)d_ws;
  unsigned short* Xb = (unsigned short*)ws;                    // 4 MiB
  float*    sq    = (float*)(ws + 4194304);                    // 32 KiB
  unsigned* pmax  = (unsigned*)(ws + 4194304 + 32768);         // 32 KiB
  unsigned* nmin  = (unsigned*)(ws + 4194304 + 65536);         // 32 KiB
  unsigned* cnt   = (unsigned*)(ws + 4194304 + 98304);         // 4 B

  prep_kernel<<<1024, 256, 0, stream>>>(X, Xb, sq, pmax, nmin, cnt);
  tile_kernel<<<NBLK, 256, 0, stream>>>(Xb, sq, tgt, pmax, nmin, cnt, out);
}

// Round 6
// 119.998 us; speedup vs baseline: 2.1092x; 1.8474x over previous
//
#include <hip/hip_runtime.h>
#include <hip/hip_bf16.h>

// TripletLoss, N=8192, D=256 fp32, targets in [0,128).
// out[0] = mean(relu(dist_ap - dist_an + 0.3)), out[1] = mean(dist_an > dist_ap)
// dist = sqrt(clip(sq_i + sq_j - 2 dot, 1e-12)); sqrt deferred (monotone);
// d2 > 0 so uint-bit order == float order -> atomicMax/Min on unsigned.
//
// R5: REMOVE the fused finish. R3/R4's __threadfence() per block lowers to
// buffer_wbl2+buffer_inv sc1 on gfx950 -> per-XCD L2 writeback+INVALIDATE per
// block (2080x!) -> Xb evicted from L2, staging latency ~2x, 3x slowdown with
// HBM bytes unchanged (LLC absorbs). Finish is its own dispatch again; the
// kernel boundary is the coherence point. K-loop stays R4's single-barrier
// double-buffer (now tested in isolation).

#define N 8192
#define D 256
#define MARGIN 0.3f
#define NBLK 2080  // 64*65/2 lower-triangle 128x128 tiles

typedef __bf16  bf16x8  __attribute__((ext_vector_type(8)));
typedef float   floatx4 __attribute__((ext_vector_type(4)));

__device__ __forceinline__ void load_lds16(const void* g, void* s) {
  __builtin_amdgcn_global_load_lds(
      (const __attribute__((address_space(1))) void*)g,
      (__attribute__((address_space(3))) void*)s, 16, 0, 0);
}

// ---------------- Kernel A: bf16 cast + row sq-norms + init ------------------
__global__ __launch_bounds__(256) void prep_kernel(
    const float* __restrict__ X, unsigned short* __restrict__ Xb,
    float* __restrict__ sq, unsigned* __restrict__ pmax, unsigned* __restrict__ nmin) {
  const int t = threadIdx.x;
  const int lane = t & 63, wave = t >> 6;
  const int row0 = blockIdx.x * 8 + wave * 2;
#pragma unroll
  for (int r = 0; r < 2; ++r) {
    const int row = row0 + r;
    float4 v = *reinterpret_cast<const float4*>(X + (size_t)row * D + lane * 4);
    ushort4 h;
    {
      __hip_bfloat16 b0 = __float2bfloat16(v.x), b1 = __float2bfloat16(v.y);
      __hip_bfloat16 b2 = __float2bfloat16(v.z), b3 = __float2bfloat16(v.w);
      h.x = *reinterpret_cast<unsigned short*>(&b0);
      h.y = *reinterpret_cast<unsigned short*>(&b1);
      h.z = *reinterpret_cast<unsigned short*>(&b2);
      h.w = *reinterpret_cast<unsigned short*>(&b3);
    }
    *reinterpret_cast<ushort4*>(Xb + (size_t)row * D + lane * 4) = h;
    float s = v.x * v.x + v.y * v.y + v.z * v.z + v.w * v.w;
#pragma unroll
    for (int o = 32; o > 0; o >>= 1) s += __shfl_down(s, o);
    if (lane == 0) {
      sq[row] = s;
      pmax[row] = 0u;
      nmin[row] = 0x7F800000u;  // +inf
    }
  }
}

// ---------------- Kernel B: triangular tiles, dbuf LDS A+B -------------------
__global__ __launch_bounds__(256) void tile_kernel(
    const unsigned short* __restrict__ Xb, const float* __restrict__ sq,
    const int* __restrict__ tgt, unsigned* __restrict__ pmax, unsigned* __restrict__ nmin) {
  // lower-triangle decode: bi -> (by >= bx)
  const int bi = blockIdx.x;
  int by = (int)((sqrtf(8.0f * (float)bi + 1.0f) - 1.0f) * 0.5f);
  while ((by + 1) * (by + 2) / 2 <= bi) ++by;
  while (by * (by + 1) / 2 > bi) --by;
  const int bx = bi - by * (by + 1) / 2;
  const int rowBase = by * 128, colBase = bx * 128;

  const int t = threadIdx.x;
  const int lane = t & 63, wave = t >> 6;
  const int wy = wave >> 1, wx = wave & 1;
  const int quad = lane >> 4, l15 = lane & 15;

  // XOR-swizzled tiles (chunk p holds global chunk (row=p>>2, c=(p&3)^(row&3)))
  __shared__ __align__(16) unsigned short As[2][128 * 32];  // 8 KB x2
  __shared__ __align__(16) unsigned short Bs[2][128 * 32];  // 8 KB x2
  __shared__ float sqr[128], sqc[128];
  __shared__ int   tr[128], tc[128];
  __shared__ unsigned pmL[128], nmL[128], pmLc[128], nmLc[128];

  if (t < 128) {
    sqr[t] = sq[rowBase + t]; tr[t] = tgt[rowBase + t];
    pmL[t] = 0u; nmL[t] = 0x7F800000u;
  } else {
    int u = t - 128;
    sqc[u] = sq[colBase + u]; tc[u] = tgt[colBase + u];
    pmLc[u] = 0u; nmLc[u] = 0x7F800000u;
  }

  const unsigned short* Ag = Xb + (size_t)rowBase * D;
  const unsigned short* Bg = Xb + (size_t)colBase * D;

  int goff[2], lbase[2];
#pragma unroll
  for (int it = 0; it < 2; ++it) {
    int p = t + it * 256;
    int row = p >> 2;
    int c = (p & 3) ^ (row & 3);
    goff[it] = row * D + c * 8;
    lbase[it] = (it * 256 + wave * 64) * 16;
  }
  int aAddr[4], bAddr[4];
#pragma unroll
  for (int mi = 0; mi < 4; ++mi) {
    int row = wy * 64 + mi * 16 + l15;
    aAddr[mi] = (row * 4 + (quad ^ (row & 3))) * 16;
  }
#pragma unroll
  for (int nj = 0; nj < 4; ++nj) {
    int col = wx * 64 + nj * 16 + l15;
    bAddr[nj] = (col * 4 + (quad ^ (col & 3))) * 16;
  }

  // prologue: issue buffer-0 DMA
#pragma unroll
  for (int it = 0; it < 2; ++it) {
    load_lds16(Ag + goff[it], (char*)As[0] + lbase[it]);
    load_lds16(Bg + goff[it], (char*)Bs[0] + lbase[it]);
  }

  floatx4 acc[4][4];
#pragma unroll
  for (int mi = 0; mi < 4; ++mi)
#pragma unroll
    for (int nj = 0; nj < 4; ++nj)
      acc[mi][nj] = (floatx4){0.f, 0.f, 0.f, 0.f};

  for (int kk = 0; kk < 8; ++kk) {
    __syncthreads();  // drains buf[kk]'s DMA (issued one compute phase ago)
    if (kk < 7) {
      int k0n = (kk + 1) * 32;
      char* an = (char*)As[(kk + 1) & 1];
      char* bn = (char*)Bs[(kk + 1) & 1];
#pragma unroll
      for (int it = 0; it < 2; ++it) {
        load_lds16(Ag + goff[it] + k0n, an + lbase[it]);
        load_lds16(Bg + goff[it] + k0n, bn + lbase[it]);
      }
    }
    const char* abuf = (const char*)As[kk & 1];
    const char* bbuf = (const char*)Bs[kk & 1];
    bf16x8 a[4], b[4];
#pragma unroll
    for (int mi = 0; mi < 4; ++mi)
      a[mi] = *reinterpret_cast<const bf16x8*>(abuf + aAddr[mi]);
#pragma unroll
    for (int nj = 0; nj < 4; ++nj)
      b[nj] = *reinterpret_cast<const bf16x8*>(bbuf + bAddr[nj]);
#pragma unroll
    for (int mi = 0; mi < 4; ++mi)
#pragma unroll
      for (int nj = 0; nj < 4; ++nj)
        acc[mi][nj] = __builtin_amdgcn_mfma_f32_16x16x32_bf16(a[mi], b[nj], acc[mi][nj], 0, 0, 0);
  }

  // ---- two-sided epilogue on clipped d2 ----
  float sqc_l[4]; int tc_l[4];
#pragma unroll
  for (int nj = 0; nj < 4; ++nj) {
    int jl = wx * 64 + nj * 16 + l15;
    sqc_l[nj] = sqc[jl];
    tc_l[nj]  = tc[jl];
  }

  float pm[16], nm[16], cmP[4], cmN[4];
#pragma unroll
  for (int s = 0; s < 16; ++s) { pm[s] = 0.f; nm[s] = __builtin_huge_valf(); }
#pragma unroll
  for (int nj = 0; nj < 4; ++nj) { cmP[nj] = 0.f; cmN[nj] = __builtin_huge_valf(); }

#pragma unroll
  for (int mi = 0; mi < 4; ++mi) {
#pragma unroll
    for (int r = 0; r < 4; ++r) {
      int il = wy * 64 + mi * 16 + quad * 4 + r;
      float si = sqr[il];
      int   ti = tr[il];
      int   s  = mi * 4 + r;
#pragma unroll
      for (int nj = 0; nj < 4; ++nj) {
        float d2 = fmaxf(fmaf(-2.f, acc[mi][nj][r], si + sqc_l[nj]), 1e-12f);
        bool same = (ti == tc_l[nj]);
        float selP = same ? d2 : 0.f;                      // no-op for max
        float selN = same ? __builtin_huge_valf() : d2;    // no-op for min
        pm[s]   = fmaxf(pm[s], selP);
        nm[s]   = fminf(nm[s], selN);
        cmP[nj] = fmaxf(cmP[nj], selP);
        cmN[nj] = fminf(cmN[nj], selN);
      }
    }
  }

  // row-side halving butterfly across 16 lanes of each quad group
#pragma unroll
  for (int m = 8; m >= 1; m >>= 1) {
#pragma unroll
    for (int j = 0; j < m; ++j) {
      bool up = (l15 & m) != 0;
      float sp = up ? pm[j] : pm[j + m];
      float sn = up ? nm[j] : nm[j + m];
      float rp = __shfl_xor(sp, m);
      float rn = __shfl_xor(sn, m);
      float kp = up ? pm[j + m] : pm[j];
      float kn = up ? nm[j + m] : nm[j];
      pm[j] = fmaxf(kp, rp);
      nm[j] = fminf(kn, rn);
    }
  }
  {
    int rowIdx = wy * 64 + ((l15 >> 2) << 4) + (quad << 2) + (l15 & 3);
    atomicMax(&pmL[rowIdx], __float_as_uint(pm[0]));
    atomicMin(&nmL[rowIdx], __float_as_uint(nm[0]));
  }

  // col-side: reduce across quads
#pragma unroll
  for (int nj = 0; nj < 4; ++nj) {
    cmP[nj] = fmaxf(cmP[nj], __shfl_xor(cmP[nj], 16));
    cmP[nj] = fmaxf(cmP[nj], __shfl_xor(cmP[nj], 32));
    cmN[nj] = fminf(cmN[nj], __shfl_xor(cmN[nj], 16));
    cmN[nj] = fminf(cmN[nj], __shfl_xor(cmN[nj], 32));
  }
  {
    float vP = (quad == 0) ? cmP[0] : (quad == 1) ? cmP[1] : (quad == 2) ? cmP[2] : cmP[3];
    float vN = (quad == 0) ? cmN[0] : (quad == 1) ? cmN[1] : (quad == 2) ? cmN[2] : cmN[3];
    int colIdx = wx * 64 + quad * 16 + l15;
    atomicMax(&pmLc[colIdx], __float_as_uint(vP));
    atomicMin(&nmLc[colIdx], __float_as_uint(vN));
  }
  __syncthreads();

  if (t < 128) {
    atomicMax(&pmax[rowBase + t], pmL[t]);
    atomicMin(&nmin[rowBase + t], nmL[t]);
  } else {
    int u = t - 128;
    atomicMax(&pmax[colBase + u], pmLc[u]);
    atomicMin(&nmin[colBase + u], nmLc[u]);
  }
}

// ---------------- Kernel C: final loss/prec (1 block) ------------------------
__global__ __launch_bounds__(256) void finish_kernel(
    const unsigned* __restrict__ pmax, const unsigned* __restrict__ nmin,
    float* __restrict__ out) {
  const int t = threadIdx.x;
  float lsum = 0.f, psum = 0.f;
  for (int i = t; i < N; i += 256) {
    float ap = sqrtf(__uint_as_float(pmax[i]));
    float an = sqrtf(__uint_as_float(nmin[i]));
    lsum += fmaxf(ap - an + MARGIN, 0.f);
    psum += (an > ap) ? 1.f : 0.f;
  }
#pragma unroll
  for (int o = 32; o > 0; o >>= 1) {
    lsum += __shfl_down(lsum, o);
    psum += __shfl_down(psum, o);
  }
  __shared__ float ls[4], ps[4];
  if ((t & 63) == 0) { ls[t >> 6] = lsum; ps[t >> 6] = psum; }
  __syncthreads();
  if (t == 0) {
    out[0] = (ls[0] + ls[1] + ls[2] + ls[3]) * (1.0f / (float)N);
    out[1] = (ps[0] + ps[1] + ps[2] + ps[3]) * (1.0f / (float)N);
  }
}

extern "C" void kernel_launch(void* const* d_in, const int* in_sizes, int n_in,
                              void* d_out, int out_size, void* d_ws, size_t ws_size,
                              hipStream_t stream) {
  const float* X  = (const float*)d_in[0];
  const int* tgt  = (const int*)d_in[1];
  float* out      = (float*)d_out;

  char* ws = (char*)d_ws;
  unsigned short* Xb = (unsigned short*)ws;                    // 4 MiB
  float*    sq    = (float*)(ws + 4194304);                    // 32 KiB
  unsigned* pmax  = (unsigned*)(ws + 4194304 + 32768);         // 32 KiB
  unsigned* nmin  = (unsigned*)(ws + 4194304 + 65536);         // 32 KiB

  prep_kernel<<<1024, 256, 0, stream>>>(X, Xb, sq, pmax, nmin);
  tile_kernel<<<NBLK, 256, 0, stream>>>(Xb, sq, tgt, pmax, nmin);
  finish_kernel<<<1, 256, 0, stream>>>(pmax, nmin, out);
}